// Round 9
// baseline (683.089 us; speedup 1.0000x reference)
//
#include <hip/hip_runtime.h>
#include <hip/hip_bf16.h>

typedef unsigned int uint;
typedef unsigned short ushort;
typedef __attribute__((ext_vector_type(8))) short bf16x8;
typedef __attribute__((ext_vector_type(4))) float f32x4;

static __device__ __forceinline__ ushort f2bf(float f) {
    uint u = __builtin_bit_cast(uint, f);
    return (ushort)((u + 0x7FFFu + ((u >> 16) & 1u)) >> 16);
}
static __device__ __forceinline__ uint pk2(float lo, float hi) {
    return (uint)f2bf(lo) | ((uint)f2bf(hi) << 16);
}
static __device__ __forceinline__ float bflo(uint u) { return __builtin_bit_cast(float, u << 16); }
static __device__ __forceinline__ float bfhi(uint u) { return __builtin_bit_cast(float, u & 0xFFFF0000u); }

// ================= CSR build: fused dual counting sort =================

#define CS_G 512

__global__ __launch_bounds__(256) void part_hist_dual(
        const int* __restrict__ src, const int* __restrict__ dst,
        uint* __restrict__ counts, int E, int NB, int chunk) {
    __shared__ uint h0[512], h1[512];
    int t = threadIdx.x;
    for (int b = t; b < 512; b += 256) { h0[b] = 0; h1[b] = 0; }
    __syncthreads();
    int s0 = blockIdx.x * chunk;
    int s1 = min(s0 + chunk, E);
    int i = s0 + t * 4;
    for (; i + 4 <= s1; i += 1024) {
        int4 d4 = *(const int4*)(dst + i);
        int4 s4 = *(const int4*)(src + i);
        atomicAdd(&h0[d4.x >> 8], 1u); atomicAdd(&h0[d4.y >> 8], 1u);
        atomicAdd(&h0[d4.z >> 8], 1u); atomicAdd(&h0[d4.w >> 8], 1u);
        atomicAdd(&h1[s4.x >> 8], 1u); atomicAdd(&h1[s4.y >> 8], 1u);
        atomicAdd(&h1[s4.z >> 8], 1u); atomicAdd(&h1[s4.w >> 8], 1u);
    }
    for (int k = i; k < min(i + 4, s1); ++k) {
        atomicAdd(&h0[dst[k] >> 8], 1u);
        atomicAdd(&h1[src[k] >> 8], 1u);
    }
    __syncthreads();
    for (int b = t; b < NB; b += 256) {
        counts[(size_t)b * CS_G + blockIdx.x] = h0[b];
        counts[(size_t)(NB + b) * CS_G + blockIdx.x] = h1[b];
    }
}

__global__ __launch_bounds__(256) void part_scatter_dual(
        const int* __restrict__ src, const int* __restrict__ dst,
        const uint* __restrict__ scn, uint* __restrict__ rec,
        int E, int NB, int chunk) {
    __shared__ uint cur0[512], cur1[512];
    int t = threadIdx.x;
    for (int b = t; b < NB; b += 256) {
        cur0[b] = scn[(size_t)b * CS_G + blockIdx.x];
        cur1[b] = scn[(size_t)(NB + b) * CS_G + blockIdx.x];
    }
    __syncthreads();
    int s0 = blockIdx.x * chunk;
    int s1 = min(s0 + chunk, E);
    int i = s0 + t * 4;
    for (; i + 4 <= s1; i += 1024) {
        int4 d4 = *(const int4*)(dst + i);
        int4 s4 = *(const int4*)(src + i);
        int dd[4] = {d4.x, d4.y, d4.z, d4.w};
        int ss[4] = {s4.x, s4.y, s4.z, s4.w};
#pragma unroll
        for (int k = 0; k < 4; ++k) {
            uint slotD = atomicAdd(&cur0[dd[k] >> 8], 1u);
            rec[slotD] = ((uint)(dd[k] & 255) << 24) | (uint)ss[k];
            uint slotS = atomicAdd(&cur1[ss[k] >> 8], 1u);
            rec[slotS] = ((uint)(ss[k] & 255) << 24) | (uint)dd[k];
        }
    }
    for (int k = i; k < min(i + 4, s1); ++k) {
        int d = dst[k], s = src[k];
        uint slotD = atomicAdd(&cur0[d >> 8], 1u);
        rec[slotD] = ((uint)(d & 255) << 24) | (uint)s;
        uint slotS = atomicAdd(&cur1[s >> 8], 1u);
        rec[slotS] = ((uint)(s & 255) << 24) | (uint)d;
    }
}

// per dst-bucket: per-node counts -> rp, dinv, deg; scatter adj
__global__ __launch_bounds__(256) void bucket_build(
        const uint* __restrict__ scn, const uint* __restrict__ rec,
        int* __restrict__ rp, int* __restrict__ adj,
        float* __restrict__ dinv, int* __restrict__ deg, int NB, int n) {
    __shared__ uint cnt[256];
    __shared__ uint sc[2][256];
    int b = blockIdx.x, t = threadIdx.x;
    uint base = scn[(size_t)b * CS_G];
    uint bend = scn[(size_t)(b + 1) * CS_G];
    cnt[t] = 0;
    __syncthreads();
    for (uint i = base + t; i < bend; i += 256)
        atomicAdd(&cnt[rec[i] >> 24], 1u);
    __syncthreads();
    uint vcnt = cnt[t];
    float dv = rsqrtf((float)(vcnt + 1));
    sc[0][t] = vcnt;
    __syncthreads();
    int pb = 0;
    for (int off = 1; off < 256; off <<= 1) {
        uint add = (t >= off) ? sc[pb][t - off] : 0u;
        sc[pb ^ 1][t] = sc[pb][t] + add;
        pb ^= 1;
        __syncthreads();
    }
    uint excl = sc[pb][t] - vcnt;
    uint off0 = base + excl;
    int vtx = b * 256 + t;
    if (vtx < n) {
        rp[vtx] = (int)off0;
        dinv[vtx] = dv;
        deg[vtx] = (int)vcnt;
    }
    if (b == 0 && t == 0) rp[n] = (int)scn[(size_t)NB * CS_G];  // = E
    cnt[t] = off0;
    __syncthreads();
    for (uint i = base + t; i < bend; i += 256) {
        uint r = rec[i];
        uint slot = atomicAdd(&cnt[r >> 24], 1u);
        adj[slot] = (int)(r & 0xFFFFFFu);
    }
}

// per src-bucket: tw via LDS atomics -> tv[v] = dv*(tw[v]+dv)
__global__ __launch_bounds__(256) void bucket_tw(
        const uint* __restrict__ scn, const uint* __restrict__ rec,
        const float* __restrict__ dinv, float* __restrict__ tv,
        int NB, int n) {
    __shared__ float tw_sh[256];
    int b = blockIdx.x, t = threadIdx.x;
    uint base = scn[(size_t)(NB + b) * CS_G];
    uint bend = scn[(size_t)(NB + b + 1) * CS_G];
    tw_sh[t] = 0.f;
    __syncthreads();
    for (uint i = base + t; i < bend; i += 256) {
        uint r = rec[i];
        atomicAdd(&tw_sh[r >> 24], dinv[r & 0xFFFFFFu]);
    }
    __syncthreads();
    int vtx = b * 256 + t;
    if (vtx < n) {
        float dv = dinv[vtx];
        tv[vtx] = dv * (tw_sh[t] + dv);
    }
}

// ================= degree-sort (counting sort, 256 bins) =================

__global__ __launch_bounds__(256) void deg_hist(
        const int* __restrict__ deg, uint* __restrict__ gh, int n) {
    __shared__ uint h[256];
    int t = threadIdx.x;
    h[t] = 0;
    __syncthreads();
    for (int i = blockIdx.x * 256 + t; i < n; i += gridDim.x * 256)
        atomicAdd(&h[min(deg[i], 255)], 1u);
    __syncthreads();
    if (h[t]) atomicAdd(&gh[t], h[t]);
}

__global__ void deg_scan(const uint* __restrict__ gh, uint* __restrict__ gcur) {
    __shared__ uint sh[256];
    int t = threadIdx.x;
    uint v = gh[t];
    sh[t] = v;
    __syncthreads();
    for (int off = 1; off < 256; off <<= 1) {
        uint u = (t >= off) ? sh[t - off] : 0u;
        __syncthreads();
        sh[t] += u;
        __syncthreads();
    }
    gcur[t] = sh[t] - v;   // exclusive
}

__global__ __launch_bounds__(256) void deg_scatter(
        const int* __restrict__ deg, uint* __restrict__ gcur,
        int* __restrict__ nodeord, int n) {
    int i = blockIdx.x * 256 + threadIdx.x;
    if (i < n) {
        uint pos = atomicAdd(&gcur[min(deg[i], 255)], 1u);
        nodeord[pos] = i;
    }
}

// ================= scan machinery =================

#define SC_T 256
#define SC_C 1024

__global__ void scan_part(const int* __restrict__ deg, int* __restrict__ bsum, int n) {
    __shared__ int sh[SC_T];
    int t = threadIdx.x;
    int base = blockIdx.x * SC_C;
    int s = 0;
    for (int i = 0; i < 4; i++) {
        int idx = base + t * 4 + i;
        if (idx < n) s += deg[idx];
    }
    sh[t] = s;
    __syncthreads();
    for (int off = 128; off > 0; off >>= 1) {
        if (t < off) sh[t] += sh[t + off];
        __syncthreads();
    }
    if (t == 0) bsum[blockIdx.x] = sh[0];
}

__global__ void scan_block(int* bsum, int nb, int* total) {
    __shared__ int sh[256];
    int t = threadIdx.x;
    int v[4];
    int s = 0;
#pragma unroll
    for (int i = 0; i < 4; i++) {
        int idx = t * 4 + i;
        v[i] = (idx < nb) ? bsum[idx] : 0;
        s += v[i];
    }
    sh[t] = s;
    __syncthreads();
    for (int off = 1; off < 256; off <<= 1) {
        int u = (t >= off) ? sh[t - off] : 0;
        __syncthreads();
        sh[t] += u;
        __syncthreads();
    }
    int excl = sh[t] - s;
#pragma unroll
    for (int i = 0; i < 4; i++) {
        int idx = t * 4 + i;
        if (idx < nb) { bsum[idx] = excl; excl += v[i]; }
    }
    if (t == 255) *total = sh[255];
}

__global__ void scan_write(const int* __restrict__ deg, const int* __restrict__ bsum,
                           const int* __restrict__ total, int* __restrict__ rp, int n) {
    __shared__ int sh[SC_T];
    int t = threadIdx.x;
    int base = blockIdx.x * SC_C;
    int vals[4];
    int s = 0;
    for (int i = 0; i < 4; i++) {
        int idx = base + t * 4 + i;
        vals[i] = (idx < n) ? deg[idx] : 0;
        s += vals[i];
    }
    sh[t] = s;
    __syncthreads();
    for (int off = 1; off < SC_T; off <<= 1) {
        int v = (t >= off) ? sh[t - off] : 0;
        __syncthreads();
        sh[t] += v;
        __syncthreads();
    }
    int excl = sh[t] - s + bsum[blockIdx.x];
    for (int i = 0; i < 4; i++) {
        int idx = base + t * 4 + i;
        if (idx < n) { rp[idx] = excl; excl += vals[i]; }
    }
    if (blockIdx.x == 0 && t == 0) rp[n] = *total;
}

// ================= W1 pre-pack =================

__global__ void pack_w(const float* __restrict__ W, ushort* __restrict__ Wp) {
    int kc = blockIdx.x >> 3, n = blockIdx.x & 7;
    int l = threadIdx.x;
    ushort o[8];
#pragma unroll
    for (int j = 0; j < 8; ++j) {
        float v = W[(size_t)(kc * 32 + ((l >> 4) * 8) + j) * 128 + n * 16 + (l & 15)];
        o[j] = f2bf(v);
    }
    uint4 pk;
    pk.x = (uint)o[0] | ((uint)o[1] << 16);
    pk.y = (uint)o[2] | ((uint)o[3] << 16);
    pk.z = (uint)o[4] | ((uint)o[5] << 16);
    pk.w = (uint)o[6] | ((uint)o[7] << 16);
    *(uint4*)(Wp + ((size_t)(kc * 8 + n) * 64 + l) * 8) = pk;
}

// ================= GEMM1: LDS-free, direct fragment loads =================

__global__ __launch_bounds__(256) void gemm1_mfma(
        const float* __restrict__ X, const ushort* __restrict__ Wp,
        ushort* __restrict__ Cb, int M, int K) {
    int t = threadIdx.x, lane = t & 63, w = t >> 6;
    int brow = blockIdx.x * 64;
    int KC = K >> 5;
    int frow = brow + w * 16 + (lane & 15);
    bool rok = frow < M;
    const float* xrow = X + (size_t)(rok ? frow : 0) * K + ((lane >> 4) * 8);
    f32x4 acc[8] = {};
    for (int kc = 0; kc < KC; ++kc) {
        float4 xa = make_float4(0.f, 0.f, 0.f, 0.f), xb = xa;
        if (rok) {
            xa = *(const float4*)(xrow + kc * 32);
            xb = *(const float4*)(xrow + kc * 32 + 4);
        }
        uint4 pk;
        pk.x = pk2(xa.x, xa.y);
        pk.y = pk2(xa.z, xa.w);
        pk.z = pk2(xb.x, xb.y);
        pk.w = pk2(xb.z, xb.w);
        bf16x8 af = __builtin_bit_cast(bf16x8, pk);
        const ushort* wbase = Wp + ((size_t)(kc * 8) * 64 + lane) * 8;
#pragma unroll
        for (int n = 0; n < 8; ++n) {
            bf16x8 bfr = *(const bf16x8*)(wbase + (size_t)n * 64 * 8);
            acc[n] = __builtin_amdgcn_mfma_f32_16x16x32_bf16(af, bfr, acc[n], 0, 0, 0);
        }
    }
    int colbase = lane & 15;
    int rowbase = brow + w * 16 + ((lane >> 4) << 2);
#pragma unroll
    for (int n = 0; n < 8; ++n) {
#pragma unroll
        for (int r = 0; r < 4; ++r) {
            int grr = rowbase + r;
            if (grr < M) Cb[(size_t)grr * 128 + n * 16 + colbase] = f2bf(acc[n][r]);
        }
    }
}

// ================= layer-1 prop, branch 0 (degree-sorted order) =================

#define ACC8(acc, g, w)                                   \
    acc[0] += bflo(g.x) * w; acc[1] += bfhi(g.x) * w;     \
    acc[2] += bflo(g.y) * w; acc[3] += bfhi(g.y) * w;     \
    acc[4] += bflo(g.z) * w; acc[5] += bfhi(g.z) * w;     \
    acc[6] += bflo(g.w) * w; acc[7] += bfhi(g.w) * w;

__global__ __launch_bounds__(256) void prop_b0(
        const ushort* __restrict__ A, const int* __restrict__ nodeord,
        const int* __restrict__ rp, const int* __restrict__ adj,
        const float* __restrict__ dinv, const float* __restrict__ tv,
        const float* __restrict__ bias,
        ushort* __restrict__ B, float* __restrict__ mparts, int n) {
    __shared__ float msum[128];
    int t = threadIdx.x;
    if (t < 128) msum[t] = 0.f;
    __syncthreads();
    int wave = (blockIdx.x * blockDim.x + t) >> 6;
    int lane = t & 63;
    int q = lane >> 4, l = lane & 15;
    int idx = wave * 4 + q;
    bool vok = idx < n;
    int vc = nodeord[vok ? idx : n - 1];
    float dv = dinv[vc];

    uint4 r0 = *(const uint4*)(A + (size_t)vc * 128 + 8 * l);
    float a0[8];
    a0[0] = bflo(r0.x) * dv; a0[1] = bfhi(r0.x) * dv;
    a0[2] = bflo(r0.y) * dv; a0[3] = bfhi(r0.y) * dv;
    a0[4] = bflo(r0.z) * dv; a0[5] = bfhi(r0.z) * dv;
    a0[6] = bflo(r0.w) * dv; a0[7] = bfhi(r0.w) * dv;

    int i = rp[vc], end = rp[vc + 1];
    int un[4];
#pragma unroll
    for (int k = 0; k < 4; ++k) un[k] = (i + k < end) ? adj[i + k] : vc;

    while (__ballot(i < end)) {
        int uc[4];
#pragma unroll
        for (int k = 0; k < 4; ++k) uc[k] = un[k];
        uint4 g0[4];
#pragma unroll
        for (int k = 0; k < 4; ++k) g0[k] = *(const uint4*)(A + (size_t)uc[k] * 128 + 8 * l);
        float du[4];
#pragma unroll
        for (int k = 0; k < 4; ++k) du[k] = (i + k < end) ? dinv[uc[k]] : 0.f;
        i += 4;
#pragma unroll
        for (int k = 0; k < 4; ++k) un[k] = (i + k < end) ? adj[i + k] : vc;
#pragma unroll
        for (int k = 0; k < 4; ++k) {
            float w = du[k];
            ACC8(a0, g0[k], w)
        }
    }
    float4 bA = *(const float4*)(bias + 8 * l);
    float4 bB = *(const float4*)(bias + 8 * l + 4);
    float bb[8] = {bA.x, bA.y, bA.z, bA.w, bB.x, bB.y, bB.z, bB.w};
#pragma unroll
    for (int j = 0; j < 8; ++j)
        a0[j] = fmaxf(a0[j] * dv + bb[j], 0.f);
    if (vok) {
        uint4 o;
        o.x = pk2(a0[0], a0[1]); o.y = pk2(a0[2], a0[3]);
        o.z = pk2(a0[4], a0[5]); o.w = pk2(a0[6], a0[7]);
        *(uint4*)(B + (size_t)vc * 128 + 8 * l) = o;
    }
    float tvv = vok ? tv[vc] : 0.f;
#pragma unroll
    for (int j = 0; j < 8; ++j)
        atomicAdd(&msum[8 * l + j], tvv * a0[j]);
    __syncthreads();
    if (t < 128)
        atomicAdd(&mparts[(size_t)(blockIdx.x & 31) * 128 + t], msum[t]);
}

// ================= branch 1 + fused dots (degree-sorted order) =================

__global__ __launch_bounds__(256) void prop_b1(
        const ushort* __restrict__ A, const ushort* __restrict__ B,
        const int* __restrict__ nodeord,
        const int* __restrict__ rp, const int* __restrict__ adj,
        const float* __restrict__ dinv, const int* __restrict__ perm,
        const float* __restrict__ bias, const float* __restrict__ w2s,
        float2* __restrict__ cpair, int n) {
    int wave = (blockIdx.x * blockDim.x + threadIdx.x) >> 6;
    int lane = threadIdx.x & 63;
    int q = lane >> 4, l = lane & 15;
    int idx = wave * 4 + q;
    bool vok = idx < n;
    int vc = nodeord[vok ? idx : n - 1];
    float dv = dinv[vc];
    int self = perm[vc];

    uint4 r1 = *(const uint4*)(A + (size_t)self * 128 + 8 * l);
    float a1[8];
    a1[0] = bflo(r1.x) * dv; a1[1] = bfhi(r1.x) * dv;
    a1[2] = bflo(r1.y) * dv; a1[3] = bfhi(r1.y) * dv;
    a1[4] = bflo(r1.z) * dv; a1[5] = bfhi(r1.z) * dv;
    a1[6] = bflo(r1.w) * dv; a1[7] = bfhi(r1.w) * dv;

    int i = rp[vc], end = rp[vc + 1];
    int un[4];
#pragma unroll
    for (int k = 0; k < 4; ++k) un[k] = (i + k < end) ? adj[i + k] : vc;

    while (__ballot(i < end)) {
        int uc[4];
#pragma unroll
        for (int k = 0; k < 4; ++k) uc[k] = un[k];
        int uu[4];
#pragma unroll
        for (int k = 0; k < 4; ++k) uu[k] = perm[uc[k]];
        uint4 g1[4];
#pragma unroll
        for (int k = 0; k < 4; ++k) g1[k] = *(const uint4*)(A + (size_t)uu[k] * 128 + 8 * l);
        float du[4];
#pragma unroll
        for (int k = 0; k < 4; ++k) du[k] = (i + k < end) ? dinv[uc[k]] : 0.f;
        i += 4;
#pragma unroll
        for (int k = 0; k < 4; ++k) un[k] = (i + k < end) ? adj[i + k] : vc;
#pragma unroll
        for (int k = 0; k < 4; ++k) {
            float w = du[k];
            ACC8(a1, g1[k], w)
        }
    }
    if (!vok) return;
    float4 bA = *(const float4*)(bias + 8 * l);
    float4 bB = *(const float4*)(bias + 8 * l + 4);
    float bb[8] = {bA.x, bA.y, bA.z, bA.w, bB.x, bB.y, bB.z, bB.w};
    float4 wA = *(const float4*)(w2s + 8 * l);
    float4 wB = *(const float4*)(w2s + 8 * l + 4);
    float ww[8] = {wA.x, wA.y, wA.z, wA.w, wB.x, wB.y, wB.z, wB.w};
    float c1 = 0.f;
#pragma unroll
    for (int j = 0; j < 8; ++j)
        c1 += fmaxf(a1[j] * dv + bb[j], 0.f) * ww[j];
    uint4 b0 = *(const uint4*)(B + (size_t)vc * 128 + 8 * l);
    float c0 = bflo(b0.x) * ww[0] + bfhi(b0.x) * ww[1]
             + bflo(b0.y) * ww[2] + bfhi(b0.y) * ww[3]
             + bflo(b0.z) * ww[4] + bfhi(b0.z) * ww[5]
             + bflo(b0.w) * ww[6] + bfhi(b0.w) * ww[7];
#pragma unroll
    for (int off = 1; off < 16; off <<= 1) {
        c0 += __shfl_xor(c0, off);
        c1 += __shfl_xor(c1, off);
    }
    if (l == 0) cpair[vc] = make_float2(dv * c0, dv * c1);
}

// ================= readout =================

__global__ void tiny_chain(const float* __restrict__ mparts, const float* __restrict__ W2,
                           const float* __restrict__ b2, const float* __restrict__ Wd,
                           const float* __restrict__ bd,
                           float* __restrict__ w2s, float* __restrict__ k0, int n) {
    __shared__ float mB[128];
    __shared__ float s_sh[128];
    __shared__ float ws_sh[128];
    __shared__ float red[128];
    int t = threadIdx.x;
    float acc = 0.f;
    for (int r = 0; r < 32; ++r) acc += mparts[(size_t)r * 128 + t];
    mB[t] = acc;
    __syncthreads();
    acc = 0.f;
    for (int k = 0; k < 128; ++k) acc += mB[k] * W2[k * 128 + t];
    float m = acc / (float)n + b2[t];
    s_sh[t] = 1.f / (1.f + expf(-m));
    __syncthreads();
    acc = 0.f;
    for (int j = 0; j < 128; ++j) acc += Wd[t * 128 + j] * s_sh[j];
    ws_sh[t] = acc;
    __syncthreads();
    acc = 0.f;
    for (int j = 0; j < 128; ++j) acc += W2[t * 128 + j] * ws_sh[j];
    w2s[t] = acc;
    red[t] = b2[t] * ws_sh[t];
    __syncthreads();
    for (int off = 64; off > 0; off >>= 1) {
        if (t < off) red[t] += red[t + off];
        __syncthreads();
    }
    if (t == 0) *k0 = red[0] + bd[0];
}

__global__ __launch_bounds__(256) void sprop(
        const float2* __restrict__ cpair,
        const int* __restrict__ rp, const int* __restrict__ adj,
        const float* __restrict__ dinv, const float* __restrict__ k0,
        float* __restrict__ out, int n) {
    int wave = (blockIdx.x * blockDim.x + threadIdx.x) >> 6;
    int lane = threadIdx.x & 63;
    int q = lane >> 4, l = lane & 15;
    int v = wave * 4 + q;
    if (v >= n) return;
    float a0 = 0.f, a1 = 0.f;
    int beg = rp[v], end = rp[v + 1];
    for (int i = beg + l; i < end; i += 16) {
        float2 c = cpair[adj[i]];
        a0 += c.x;
        a1 += c.y;
    }
#pragma unroll
    for (int off = 1; off < 16; off <<= 1) {
        a0 += __shfl_xor(a0, off);
        a1 += __shfl_xor(a1, off);
    }
    if (l == 0) {
        float dv = dinv[v];
        float kk = *k0;
        float2 cs = cpair[v];
        out[v] = dv * (a0 + cs.x) + kk;
        out[n + v] = dv * (a1 + cs.y) + kk;
    }
}

// ================= launch =================

extern "C" void kernel_launch(void* const* d_in, const int* in_sizes, int n_in,
                              void* d_out, int out_size, void* d_ws, size_t ws_size,
                              hipStream_t stream) {
    const float* x  = (const float*)d_in[0];
    const int*   ei = (const int*)d_in[1];
    const int* perm = (const int*)d_in[2];
    const float* W1 = (const float*)d_in[3];
    const float* b1 = (const float*)d_in[4];
    const float* W2 = (const float*)d_in[5];
    const float* b2 = (const float*)d_in[6];
    const float* Wd = (const float*)d_in[7];
    const float* bd = (const float*)d_in[8];

    const int N = in_sizes[2];
    const int E = in_sizes[1] / 2;
    const int IN = in_sizes[0] / N;  // 512
    const int* src = ei;
    const int* dst = ei + E;
    float* out = (float*)d_out;

    const int NB = (N + 255) >> 8;
    const int M2 = 2 * NB * CS_G;
    int chunk = (E + CS_G - 1) / CS_G;
    chunk = (chunk + 3) & ~3;

    char* p = (char*)d_ws;
    auto alloc = [&](size_t bytes) -> void* {
        void* r = (void*)p;
        p += (bytes + 511) & ~(size_t)511;
        return r;
    };
    float* mparts = (float*)alloc(32 * 128 * 4);   // zero group start
    uint*  gh     = (uint*)alloc(1024);
    size_t zspan  = (size_t)((char*)p - (char*)mparts);
    uint*  gcur   = (uint*)alloc(1024);
    uint*  counts = (uint*)alloc((size_t)M2 * 4);
    uint*  scn    = (uint*)alloc((size_t)(M2 + 1) * 4);
    uint*  rec    = (uint*)alloc((size_t)2 * E * 4);
    int*   rp     = (int*)alloc((size_t)(N + 1) * 4);
    int*   adj    = (int*)alloc((size_t)E * 4);
    float* dinv   = (float*)alloc((size_t)N * 4);
    float* tvv    = (float*)alloc((size_t)N * 4);
    int*   deg    = (int*)alloc((size_t)N * 4);
    int*   nodeord= (int*)alloc((size_t)N * 4);
    int*   bsum   = (int*)alloc(4096);
    int*   total  = (int*)alloc(64);
    float* w2sv   = (float*)alloc(512);
    float* k0v    = (float*)alloc(64);
    float2* cpair = (float2*)alloc((size_t)N * 8);
    ushort* W1p   = (ushort*)alloc((size_t)512 * 128 * 2);
    ushort* A  = (ushort*)alloc((size_t)N * 128 * 2);
    ushort* B  = (ushort*)alloc((size_t)N * 128 * 2);

    hipMemsetAsync(mparts, 0, zspan, stream);

    // --- fused dual counting sort ---
    part_hist_dual<<<CS_G, 256, 0, stream>>>(src, dst, counts, E, NB, chunk);
    int nb_sc = (M2 + SC_C - 1) / SC_C;
    scan_part<<<nb_sc, SC_T, 0, stream>>>((const int*)counts, bsum, M2);
    scan_block<<<1, 256, 0, stream>>>(bsum, nb_sc, total);
    scan_write<<<nb_sc, SC_T, 0, stream>>>((const int*)counts, bsum, total, (int*)scn, M2);
    part_scatter_dual<<<CS_G, 256, 0, stream>>>(src, dst, scn, rec, E, NB, chunk);
    bucket_build<<<NB, 256, 0, stream>>>(scn, rec, rp, adj, dinv, deg, NB, N);
    bucket_tw<<<NB, 256, 0, stream>>>(scn, rec, dinv, tvv, NB, N);

    // --- degree sort ---
    deg_hist<<<128, 256, 0, stream>>>(deg, gh, N);
    deg_scan<<<1, 256, 0, stream>>>(gh, gcur);
    deg_scatter<<<(N + 255) / 256, 256, 0, stream>>>(deg, gcur, nodeord, N);

    // --- dense pipeline ---
    pack_w<<<(IN / 32) * 8, 64, 0, stream>>>(W1, W1p);

    int gemm_blocks = (N + 63) / 64;
    int p4_blocks = ((N + 3) / 4 + 3) / 4;

    gemm1_mfma<<<gemm_blocks, 256, 0, stream>>>(x, W1p, A, N, IN);
    prop_b0<<<p4_blocks, 256, 0, stream>>>(A, nodeord, rp, adj, dinv, tvv, b1, B, mparts, N);
    tiny_chain<<<1, 128, 0, stream>>>(mparts, W2, b2, Wd, bd, w2sv, k0v, N);
    prop_b1<<<p4_blocks, 256, 0, stream>>>(A, B, nodeord, rp, adj, dinv, perm, b1, w2sv, cpair, N);
    sprop<<<p4_blocks, 256, 0, stream>>>(cpair, rp, adj, dinv, k0v, out, N);
}

// Round 10
// 493.588 us; speedup vs baseline: 1.3839x; 1.3839x over previous
//
#include <hip/hip_runtime.h>
#include <hip/hip_bf16.h>

typedef unsigned int uint;
typedef unsigned short ushort;
typedef __attribute__((ext_vector_type(8))) short bf16x8;
typedef __attribute__((ext_vector_type(4))) float f32x4;

static __device__ __forceinline__ ushort f2bf(float f) {
    uint u = __builtin_bit_cast(uint, f);
    return (ushort)((u + 0x7FFFu + ((u >> 16) & 1u)) >> 16);
}
static __device__ __forceinline__ uint pk2(float lo, float hi) {
    return (uint)f2bf(lo) | ((uint)f2bf(hi) << 16);
}
static __device__ __forceinline__ float bflo(uint u) { return __builtin_bit_cast(float, u << 16); }
static __device__ __forceinline__ float bfhi(uint u) { return __builtin_bit_cast(float, u & 0xFFFF0000u); }

// ================= CSR build: fused dual counting sort =================
// dst-sort -> adj (in-neighbors); src-sort -> records for tw reduction.
// bucket = node >> 8 (256 nodes per bucket). NB <= 512. Node ids < 2^24.

#define CS_G 512

__global__ __launch_bounds__(256) void part_hist_dual(
        const int* __restrict__ src, const int* __restrict__ dst,
        uint* __restrict__ counts, int E, int NB, int chunk) {
    __shared__ uint h0[512], h1[512];
    int t = threadIdx.x;
    for (int b = t; b < 512; b += 256) { h0[b] = 0; h1[b] = 0; }
    __syncthreads();
    int s0 = blockIdx.x * chunk;
    int s1 = min(s0 + chunk, E);
    int i = s0 + t * 4;
    for (; i + 4 <= s1; i += 1024) {
        int4 d4 = *(const int4*)(dst + i);
        int4 s4 = *(const int4*)(src + i);
        atomicAdd(&h0[d4.x >> 8], 1u); atomicAdd(&h0[d4.y >> 8], 1u);
        atomicAdd(&h0[d4.z >> 8], 1u); atomicAdd(&h0[d4.w >> 8], 1u);
        atomicAdd(&h1[s4.x >> 8], 1u); atomicAdd(&h1[s4.y >> 8], 1u);
        atomicAdd(&h1[s4.z >> 8], 1u); atomicAdd(&h1[s4.w >> 8], 1u);
    }
    for (int k = i; k < min(i + 4, s1); ++k) {
        atomicAdd(&h0[dst[k] >> 8], 1u);
        atomicAdd(&h1[src[k] >> 8], 1u);
    }
    __syncthreads();
    for (int b = t; b < NB; b += 256) {
        counts[(size_t)b * CS_G + blockIdx.x] = h0[b];
        counts[(size_t)(NB + b) * CS_G + blockIdx.x] = h1[b];
    }
}

__global__ __launch_bounds__(256) void part_scatter_dual(
        const int* __restrict__ src, const int* __restrict__ dst,
        const uint* __restrict__ scn, uint* __restrict__ rec,
        int E, int NB, int chunk) {
    __shared__ uint cur0[512], cur1[512];
    int t = threadIdx.x;
    for (int b = t; b < NB; b += 256) {
        cur0[b] = scn[(size_t)b * CS_G + blockIdx.x];
        cur1[b] = scn[(size_t)(NB + b) * CS_G + blockIdx.x];
    }
    __syncthreads();
    int s0 = blockIdx.x * chunk;
    int s1 = min(s0 + chunk, E);
    int i = s0 + t * 4;
    for (; i + 4 <= s1; i += 1024) {
        int4 d4 = *(const int4*)(dst + i);
        int4 s4 = *(const int4*)(src + i);
        int dd[4] = {d4.x, d4.y, d4.z, d4.w};
        int ss[4] = {s4.x, s4.y, s4.z, s4.w};
#pragma unroll
        for (int k = 0; k < 4; ++k) {
            uint slotD = atomicAdd(&cur0[dd[k] >> 8], 1u);
            rec[slotD] = ((uint)(dd[k] & 255) << 24) | (uint)ss[k];
            uint slotS = atomicAdd(&cur1[ss[k] >> 8], 1u);
            rec[slotS] = ((uint)(ss[k] & 255) << 24) | (uint)dd[k];
        }
    }
    for (int k = i; k < min(i + 4, s1); ++k) {
        int d = dst[k], s = src[k];
        uint slotD = atomicAdd(&cur0[d >> 8], 1u);
        rec[slotD] = ((uint)(d & 255) << 24) | (uint)s;
        uint slotS = atomicAdd(&cur1[s >> 8], 1u);
        rec[slotS] = ((uint)(s & 255) << 24) | (uint)d;
    }
}

// per dst-bucket: per-node counts -> rp, dinv; scatter adj
__global__ __launch_bounds__(256) void bucket_build(
        const uint* __restrict__ scn, const uint* __restrict__ rec,
        int* __restrict__ rp, int* __restrict__ adj,
        float* __restrict__ dinv, int NB, int n) {
    __shared__ uint cnt[256];
    __shared__ uint sc[2][256];
    int b = blockIdx.x, t = threadIdx.x;
    uint base = scn[(size_t)b * CS_G];
    uint bend = scn[(size_t)(b + 1) * CS_G];
    cnt[t] = 0;
    __syncthreads();
    for (uint i = base + t; i < bend; i += 256)
        atomicAdd(&cnt[rec[i] >> 24], 1u);
    __syncthreads();
    uint vcnt = cnt[t];
    float dv = rsqrtf((float)(vcnt + 1));
    sc[0][t] = vcnt;
    __syncthreads();
    int pb = 0;
    for (int off = 1; off < 256; off <<= 1) {
        uint add = (t >= off) ? sc[pb][t - off] : 0u;
        sc[pb ^ 1][t] = sc[pb][t] + add;
        pb ^= 1;
        __syncthreads();
    }
    uint excl = sc[pb][t] - vcnt;
    uint off0 = base + excl;
    int vtx = b * 256 + t;
    if (vtx < n) {
        rp[vtx] = (int)off0;
        dinv[vtx] = dv;
    }
    if (b == 0 && t == 0) rp[n] = (int)scn[(size_t)NB * CS_G];  // = E
    cnt[t] = off0;
    __syncthreads();
    for (uint i = base + t; i < bend; i += 256) {
        uint r = rec[i];
        uint slot = atomicAdd(&cnt[r >> 24], 1u);
        adj[slot] = (int)(r & 0xFFFFFFu);
    }
}

// per src-bucket: tw via LDS atomics -> tv[v] = dv*(tw[v]+dv)
__global__ __launch_bounds__(256) void bucket_tw(
        const uint* __restrict__ scn, const uint* __restrict__ rec,
        const float* __restrict__ dinv, float* __restrict__ tv,
        int NB, int n) {
    __shared__ float tw_sh[256];
    int b = blockIdx.x, t = threadIdx.x;
    uint base = scn[(size_t)(NB + b) * CS_G];
    uint bend = scn[(size_t)(NB + b + 1) * CS_G];
    tw_sh[t] = 0.f;
    __syncthreads();
    for (uint i = base + t; i < bend; i += 256) {
        uint r = rec[i];
        atomicAdd(&tw_sh[r >> 24], dinv[r & 0xFFFFFFu]);
    }
    __syncthreads();
    int vtx = b * 256 + t;
    if (vtx < n) {
        float dv = dinv[vtx];
        tv[vtx] = dv * (tw_sh[t] + dv);
    }
}

// ================= scan machinery =================

#define SC_T 256
#define SC_C 1024

__global__ void scan_part(const int* __restrict__ deg, int* __restrict__ bsum, int n) {
    __shared__ int sh[SC_T];
    int t = threadIdx.x;
    int base = blockIdx.x * SC_C;
    int s = 0;
    for (int i = 0; i < 4; i++) {
        int idx = base + t * 4 + i;
        if (idx < n) s += deg[idx];
    }
    sh[t] = s;
    __syncthreads();
    for (int off = 128; off > 0; off >>= 1) {
        if (t < off) sh[t] += sh[t + off];
        __syncthreads();
    }
    if (t == 0) bsum[blockIdx.x] = sh[0];
}

__global__ void scan_block(int* bsum, int nb, int* total) {
    __shared__ int sh[256];
    int t = threadIdx.x;
    int v[4];
    int s = 0;
#pragma unroll
    for (int i = 0; i < 4; i++) {
        int idx = t * 4 + i;
        v[i] = (idx < nb) ? bsum[idx] : 0;
        s += v[i];
    }
    sh[t] = s;
    __syncthreads();
    for (int off = 1; off < 256; off <<= 1) {
        int u = (t >= off) ? sh[t - off] : 0;
        __syncthreads();
        sh[t] += u;
        __syncthreads();
    }
    int excl = sh[t] - s;
#pragma unroll
    for (int i = 0; i < 4; i++) {
        int idx = t * 4 + i;
        if (idx < nb) { bsum[idx] = excl; excl += v[i]; }
    }
    if (t == 255) *total = sh[255];
}

__global__ void scan_write(const int* __restrict__ deg, const int* __restrict__ bsum,
                           const int* __restrict__ total, int* __restrict__ rp, int n) {
    __shared__ int sh[SC_T];
    int t = threadIdx.x;
    int base = blockIdx.x * SC_C;
    int vals[4];
    int s = 0;
    for (int i = 0; i < 4; i++) {
        int idx = base + t * 4 + i;
        vals[i] = (idx < n) ? deg[idx] : 0;
        s += vals[i];
    }
    sh[t] = s;
    __syncthreads();
    for (int off = 1; off < SC_T; off <<= 1) {
        int v = (t >= off) ? sh[t - off] : 0;
        __syncthreads();
        sh[t] += v;
        __syncthreads();
    }
    int excl = sh[t] - s + bsum[blockIdx.x];
    for (int i = 0; i < 4; i++) {
        int idx = base + t * 4 + i;
        if (idx < n) { rp[idx] = excl; excl += vals[i]; }
    }
    if (blockIdx.x == 0 && t == 0) rp[n] = *total;
}

// ================= W1 pre-pack into MFMA B-fragment layout =================

__global__ void pack_w(const float* __restrict__ W, ushort* __restrict__ Wp) {
    int kc = blockIdx.x >> 3, n = blockIdx.x & 7;
    int l = threadIdx.x;
    ushort o[8];
#pragma unroll
    for (int j = 0; j < 8; ++j) {
        float v = W[(size_t)(kc * 32 + ((l >> 4) * 8) + j) * 128 + n * 16 + (l & 15)];
        o[j] = f2bf(v);
    }
    uint4 pk;
    pk.x = (uint)o[0] | ((uint)o[1] << 16);
    pk.y = (uint)o[2] | ((uint)o[3] << 16);
    pk.z = (uint)o[4] | ((uint)o[5] << 16);
    pk.w = (uint)o[6] | ((uint)o[7] << 16);
    *(uint4*)(Wp + ((size_t)(kc * 8 + n) * 64 + l) * 8) = pk;
}

// ================= GEMM1: LDS-free, direct fragment loads =================

__global__ __launch_bounds__(256) void gemm1_mfma(
        const float* __restrict__ X, const ushort* __restrict__ Wp,
        ushort* __restrict__ Cb, int M, int K) {
    int t = threadIdx.x, lane = t & 63, w = t >> 6;
    int brow = blockIdx.x * 64;
    int KC = K >> 5;
    int frow = brow + w * 16 + (lane & 15);
    bool rok = frow < M;
    const float* xrow = X + (size_t)(rok ? frow : 0) * K + ((lane >> 4) * 8);
    f32x4 acc[8] = {};
    for (int kc = 0; kc < KC; ++kc) {
        float4 xa = make_float4(0.f, 0.f, 0.f, 0.f), xb = xa;
        if (rok) {
            xa = *(const float4*)(xrow + kc * 32);
            xb = *(const float4*)(xrow + kc * 32 + 4);
        }
        uint4 pk;
        pk.x = pk2(xa.x, xa.y);
        pk.y = pk2(xa.z, xa.w);
        pk.z = pk2(xb.x, xb.y);
        pk.w = pk2(xb.z, xb.w);
        bf16x8 af = __builtin_bit_cast(bf16x8, pk);
        const ushort* wbase = Wp + ((size_t)(kc * 8) * 64 + lane) * 8;
#pragma unroll
        for (int n = 0; n < 8; ++n) {
            bf16x8 bfr = *(const bf16x8*)(wbase + (size_t)n * 64 * 8);
            acc[n] = __builtin_amdgcn_mfma_f32_16x16x32_bf16(af, bfr, acc[n], 0, 0, 0);
        }
    }
    int colbase = lane & 15;
    int rowbase = brow + w * 16 + ((lane >> 4) << 2);
#pragma unroll
    for (int n = 0; n < 8; ++n) {
#pragma unroll
        for (int r = 0; r < 4; ++r) {
            int grr = rowbase + r;
            if (grr < M) Cb[(size_t)grr * 128 + n * 16 + colbase] = f2bf(acc[n][r]);
        }
    }
}

// ================= layer-1 prop, branch 0: B = relu(S*A + b1), fused weighted colsum =================

#define ACC8(acc, g, w)                                   \
    acc[0] += bflo(g.x) * w; acc[1] += bfhi(g.x) * w;     \
    acc[2] += bflo(g.y) * w; acc[3] += bfhi(g.y) * w;     \
    acc[4] += bflo(g.z) * w; acc[5] += bfhi(g.z) * w;     \
    acc[6] += bflo(g.w) * w; acc[7] += bfhi(g.w) * w;

__global__ __launch_bounds__(256) void prop_b0(
        const ushort* __restrict__ A,
        const int* __restrict__ rp, const int* __restrict__ adj,
        const float* __restrict__ dinv, const float* __restrict__ tv,
        const float* __restrict__ bias,
        ushort* __restrict__ B, float* __restrict__ mparts, int n) {
    __shared__ float msum[128];
    int t = threadIdx.x;
    if (t < 128) msum[t] = 0.f;
    __syncthreads();
    int wave = (blockIdx.x * blockDim.x + t) >> 6;
    int lane = t & 63;
    int q = lane >> 4, l = lane & 15;
    int v = wave * 4 + q;
    bool vok = v < n;
    int vc = vok ? v : (n - 1);
    float dv = dinv[vc];

    uint4 r0 = *(const uint4*)(A + (size_t)vc * 128 + 8 * l);
    float a0[8];
    a0[0] = bflo(r0.x) * dv; a0[1] = bfhi(r0.x) * dv;
    a0[2] = bflo(r0.y) * dv; a0[3] = bfhi(r0.y) * dv;
    a0[4] = bflo(r0.z) * dv; a0[5] = bfhi(r0.z) * dv;
    a0[6] = bflo(r0.w) * dv; a0[7] = bfhi(r0.w) * dv;

    int i = rp[vc], end = rp[vc + 1];
    int un[4];
#pragma unroll
    for (int k = 0; k < 4; ++k) un[k] = (i + k < end) ? adj[i + k] : vc;

    while (__ballot(i < end)) {
        int uc[4];
#pragma unroll
        for (int k = 0; k < 4; ++k) uc[k] = un[k];
        uint4 g0[4];
#pragma unroll
        for (int k = 0; k < 4; ++k) g0[k] = *(const uint4*)(A + (size_t)uc[k] * 128 + 8 * l);
        float du[4];
#pragma unroll
        for (int k = 0; k < 4; ++k) du[k] = (i + k < end) ? dinv[uc[k]] : 0.f;
        i += 4;
#pragma unroll
        for (int k = 0; k < 4; ++k) un[k] = (i + k < end) ? adj[i + k] : vc;
#pragma unroll
        for (int k = 0; k < 4; ++k) {
            float w = du[k];
            ACC8(a0, g0[k], w)
        }
    }
    float4 bA = *(const float4*)(bias + 8 * l);
    float4 bB = *(const float4*)(bias + 8 * l + 4);
    float bb[8] = {bA.x, bA.y, bA.z, bA.w, bB.x, bB.y, bB.z, bB.w};
#pragma unroll
    for (int j = 0; j < 8; ++j)
        a0[j] = fmaxf(a0[j] * dv + bb[j], 0.f);
    if (vok) {
        uint4 o;
        o.x = pk2(a0[0], a0[1]); o.y = pk2(a0[2], a0[3]);
        o.z = pk2(a0[4], a0[5]); o.w = pk2(a0[6], a0[7]);
        *(uint4*)(B + (size_t)v * 128 + 8 * l) = o;
    }
    float tvv = vok ? tv[vc] : 0.f;
#pragma unroll
    for (int j = 0; j < 8; ++j)
        atomicAdd(&msum[8 * l + j], tvv * a0[j]);
    __syncthreads();
    if (t < 128)
        atomicAdd(&mparts[(size_t)(blockIdx.x & 31) * 128 + t], msum[t]);
}

// ================= branch 1 + fused dots =================

__global__ __launch_bounds__(256) void prop_b1(
        const ushort* __restrict__ A, const ushort* __restrict__ B,
        const int* __restrict__ rp, const int* __restrict__ adj,
        const float* __restrict__ dinv, const int* __restrict__ perm,
        const float* __restrict__ bias, const float* __restrict__ w2s,
        float2* __restrict__ cpair, int n) {
    int wave = (blockIdx.x * blockDim.x + threadIdx.x) >> 6;
    int lane = threadIdx.x & 63;
    int q = lane >> 4, l = lane & 15;
    int v = wave * 4 + q;
    bool vok = v < n;
    int vc = vok ? v : (n - 1);
    float dv = dinv[vc];
    int self = perm[vc];

    uint4 r1 = *(const uint4*)(A + (size_t)self * 128 + 8 * l);
    float a1[8];
    a1[0] = bflo(r1.x) * dv; a1[1] = bfhi(r1.x) * dv;
    a1[2] = bflo(r1.y) * dv; a1[3] = bfhi(r1.y) * dv;
    a1[4] = bflo(r1.z) * dv; a1[5] = bfhi(r1.z) * dv;
    a1[6] = bflo(r1.w) * dv; a1[7] = bfhi(r1.w) * dv;

    int i = rp[vc], end = rp[vc + 1];
    int un[4];
#pragma unroll
    for (int k = 0; k < 4; ++k) un[k] = (i + k < end) ? adj[i + k] : vc;

    while (__ballot(i < end)) {
        int uc[4];
#pragma unroll
        for (int k = 0; k < 4; ++k) uc[k] = un[k];
        int uu[4];
#pragma unroll
        for (int k = 0; k < 4; ++k) uu[k] = perm[uc[k]];
        uint4 g1[4];
#pragma unroll
        for (int k = 0; k < 4; ++k) g1[k] = *(const uint4*)(A + (size_t)uu[k] * 128 + 8 * l);
        float du[4];
#pragma unroll
        for (int k = 0; k < 4; ++k) du[k] = (i + k < end) ? dinv[uc[k]] : 0.f;
        i += 4;
#pragma unroll
        for (int k = 0; k < 4; ++k) un[k] = (i + k < end) ? adj[i + k] : vc;
#pragma unroll
        for (int k = 0; k < 4; ++k) {
            float w = du[k];
            ACC8(a1, g1[k], w)
        }
    }
    if (!vok) return;
    float4 bA = *(const float4*)(bias + 8 * l);
    float4 bB = *(const float4*)(bias + 8 * l + 4);
    float bb[8] = {bA.x, bA.y, bA.z, bA.w, bB.x, bB.y, bB.z, bB.w};
    float4 wA = *(const float4*)(w2s + 8 * l);
    float4 wB = *(const float4*)(w2s + 8 * l + 4);
    float ww[8] = {wA.x, wA.y, wA.z, wA.w, wB.x, wB.y, wB.z, wB.w};
    float c1 = 0.f;
#pragma unroll
    for (int j = 0; j < 8; ++j)
        c1 += fmaxf(a1[j] * dv + bb[j], 0.f) * ww[j];
    uint4 b0 = *(const uint4*)(B + (size_t)vc * 128 + 8 * l);
    float c0 = bflo(b0.x) * ww[0] + bfhi(b0.x) * ww[1]
             + bflo(b0.y) * ww[2] + bfhi(b0.y) * ww[3]
             + bflo(b0.z) * ww[4] + bfhi(b0.z) * ww[5]
             + bflo(b0.w) * ww[6] + bfhi(b0.w) * ww[7];
#pragma unroll
    for (int off = 1; off < 16; off <<= 1) {
        c0 += __shfl_xor(c0, off);
        c1 += __shfl_xor(c1, off);
    }
    if (l == 0) cpair[v] = make_float2(dv * c0, dv * c1);
}

// ================= readout =================

__global__ void tiny_chain(const float* __restrict__ mparts, const float* __restrict__ W2,
                           const float* __restrict__ b2, const float* __restrict__ Wd,
                           const float* __restrict__ bd,
                           float* __restrict__ w2s, float* __restrict__ k0, int n) {
    __shared__ float mB[128];
    __shared__ float s_sh[128];
    __shared__ float ws_sh[128];
    __shared__ float red[128];
    int t = threadIdx.x;
    float acc = 0.f;
    for (int r = 0; r < 32; ++r) acc += mparts[(size_t)r * 128 + t];
    mB[t] = acc;
    __syncthreads();
    acc = 0.f;
    for (int k = 0; k < 128; ++k) acc += mB[k] * W2[k * 128 + t];
    float m = acc / (float)n + b2[t];
    s_sh[t] = 1.f / (1.f + expf(-m));
    __syncthreads();
    acc = 0.f;
    for (int j = 0; j < 128; ++j) acc += Wd[t * 128 + j] * s_sh[j];
    ws_sh[t] = acc;
    __syncthreads();
    acc = 0.f;
    for (int j = 0; j < 128; ++j) acc += W2[t * 128 + j] * ws_sh[j];
    w2s[t] = acc;
    red[t] = b2[t] * ws_sh[t];
    __syncthreads();
    for (int off = 64; off > 0; off >>= 1) {
        if (t < off) red[t] += red[t + off];
        __syncthreads();
    }
    if (t == 0) *k0 = red[0] + bd[0];
}

__global__ __launch_bounds__(256) void sprop(
        const float2* __restrict__ cpair,
        const int* __restrict__ rp, const int* __restrict__ adj,
        const float* __restrict__ dinv, const float* __restrict__ k0,
        float* __restrict__ out, int n) {
    int wave = (blockIdx.x * blockDim.x + threadIdx.x) >> 6;
    int lane = threadIdx.x & 63;
    int q = lane >> 4, l = lane & 15;
    int v = wave * 4 + q;
    if (v >= n) return;
    float a0 = 0.f, a1 = 0.f;
    int beg = rp[v], end = rp[v + 1];
    for (int i = beg + l; i < end; i += 16) {
        float2 c = cpair[adj[i]];
        a0 += c.x;
        a1 += c.y;
    }
#pragma unroll
    for (int off = 1; off < 16; off <<= 1) {
        a0 += __shfl_xor(a0, off);
        a1 += __shfl_xor(a1, off);
    }
    if (l == 0) {
        float dv = dinv[v];
        float kk = *k0;
        float2 cs = cpair[v];
        out[v] = dv * (a0 + cs.x) + kk;
        out[n + v] = dv * (a1 + cs.y) + kk;
    }
}

// ================= launch =================

extern "C" void kernel_launch(void* const* d_in, const int* in_sizes, int n_in,
                              void* d_out, int out_size, void* d_ws, size_t ws_size,
                              hipStream_t stream) {
    const float* x  = (const float*)d_in[0];
    const int*   ei = (const int*)d_in[1];
    const int* perm = (const int*)d_in[2];
    const float* W1 = (const float*)d_in[3];
    const float* b1 = (const float*)d_in[4];
    const float* W2 = (const float*)d_in[5];
    const float* b2 = (const float*)d_in[6];
    const float* Wd = (const float*)d_in[7];
    const float* bd = (const float*)d_in[8];

    const int N = in_sizes[2];
    const int E = in_sizes[1] / 2;
    const int IN = in_sizes[0] / N;  // 512
    const int* src = ei;
    const int* dst = ei + E;
    float* out = (float*)d_out;

    const int NB = (N + 255) >> 8;
    const int M2 = 2 * NB * CS_G;
    int chunk = (E + CS_G - 1) / CS_G;
    chunk = (chunk + 3) & ~3;

    char* p = (char*)d_ws;
    auto alloc = [&](size_t bytes) -> void* {
        void* r = (void*)p;
        p += (bytes + 511) & ~(size_t)511;
        return r;
    };
    float* mparts = (float*)alloc(32 * 128 * 4);   // zeroed each call
    uint*  counts = (uint*)alloc((size_t)M2 * 4);
    uint*  scn    = (uint*)alloc((size_t)(M2 + 1) * 4);
    uint*  rec    = (uint*)alloc((size_t)2 * E * 4);
    int*   rp     = (int*)alloc((size_t)(N + 1) * 4);
    int*   adj    = (int*)alloc((size_t)E * 4);
    float* dinv   = (float*)alloc((size_t)N * 4);
    float* tvv    = (float*)alloc((size_t)N * 4);
    int*   bsum   = (int*)alloc(4096);
    int*   total  = (int*)alloc(64);
    float* w2sv   = (float*)alloc(512);
    float* k0v    = (float*)alloc(64);
    float2* cpair = (float2*)alloc((size_t)N * 8);
    ushort* W1p   = (ushort*)alloc((size_t)512 * 128 * 2);
    ushort* A  = (ushort*)alloc((size_t)N * 128 * 2);
    ushort* B  = (ushort*)alloc((size_t)N * 128 * 2);

    hipMemsetAsync(mparts, 0, 32 * 128 * 4, stream);

    // --- fused dual counting sort ---
    part_hist_dual<<<CS_G, 256, 0, stream>>>(src, dst, counts, E, NB, chunk);
    int nb_sc = (M2 + SC_C - 1) / SC_C;
    scan_part<<<nb_sc, SC_T, 0, stream>>>((const int*)counts, bsum, M2);
    scan_block<<<1, 256, 0, stream>>>(bsum, nb_sc, total);
    scan_write<<<nb_sc, SC_T, 0, stream>>>((const int*)counts, bsum, total, (int*)scn, M2);
    part_scatter_dual<<<CS_G, 256, 0, stream>>>(src, dst, scn, rec, E, NB, chunk);
    bucket_build<<<NB, 256, 0, stream>>>(scn, rec, rp, adj, dinv, NB, N);
    bucket_tw<<<NB, 256, 0, stream>>>(scn, rec, dinv, tvv, NB, N);

    // --- dense pipeline ---
    pack_w<<<(IN / 32) * 8, 64, 0, stream>>>(W1, W1p);

    int gemm_blocks = (N + 63) / 64;
    int p4_blocks = ((N + 3) / 4 + 3) / 4;

    gemm1_mfma<<<gemm_blocks, 256, 0, stream>>>(x, W1p, A, N, IN);
    prop_b0<<<p4_blocks, 256, 0, stream>>>(A, rp, adj, dinv, tvv, b1, B, mparts, N);
    tiny_chain<<<1, 128, 0, stream>>>(mparts, W2, b2, Wd, bd, w2sv, k0v, N);
    prop_b1<<<p4_blocks, 256, 0, stream>>>(A, B, rp, adj, dinv, perm, b1, w2sv, cpair, N);
    sprop<<<p4_blocks, 256, 0, stream>>>(cpair, rp, adj, dinv, k0v, out, N);
}